// Round 1
// baseline (313.288 us; speedup 1.0000x reference)
//
#include <hip/hip_runtime.h>

// VQ-VAE embedding quantization (eval mode), MI355X fp32.
// x: [32,64,64,64] -> 131072 vectors of dim 64; embedding: [512,64].
// Outputs concatenated in d_out: quantized_st [8388608] | loss [1] | perplexity [1].

#define D      64
#define M      512
#define N_VEC  131072
#define N_ELEM 8388608

// ws layout: [0] float loss_sum; [1..512] unsigned int counts
__global__ __launch_bounds__(256, 2)
void vq_main(const float* __restrict__ x, const float* __restrict__ emb,
             float* __restrict__ out, float* __restrict__ loss_sum,
             unsigned int* __restrict__ counts) {
    __shared__ float sE[M];           // ||e_c||^2
    __shared__ unsigned int sHist[M];
    __shared__ float sRed[4];

    const int tid = threadIdx.x;

    // Precompute ||e_c||^2 into LDS (2 codes per thread); zero LDS histogram.
    for (int c = tid; c < M; c += 256) {
        const float* e = emb + c * D;
        float s0 = 0.f, s1 = 0.f, s2 = 0.f, s3 = 0.f;
#pragma unroll
        for (int k = 0; k < D; k += 4) {
            s0 = fmaf(e[k + 0], e[k + 0], s0);
            s1 = fmaf(e[k + 1], e[k + 1], s1);
            s2 = fmaf(e[k + 2], e[k + 2], s2);
            s3 = fmaf(e[k + 3], e[k + 3], s3);
        }
        sE[c] = (s0 + s1) + (s2 + s3);
        sHist[c] = 0u;
    }
    __syncthreads();

    const int i = blockIdx.x * 256 + tid;    // vector index, grid exactly covers N_VEC
    const float4* xv = reinterpret_cast<const float4*>(x + (size_t)i * D);
    float4 xr[16];
#pragma unroll
    for (int t = 0; t < 16; ++t) xr[t] = xv[t];

    // A = ||x_i||^2, pairwise tree (reference computes d2 at this ~64 scale).
    float A;
    {
        float p[16];
#pragma unroll
        for (int t = 0; t < 16; ++t)
            p[t] = (xr[t].x * xr[t].x + xr[t].y * xr[t].y) +
                   (xr[t].z * xr[t].z + xr[t].w * xr[t].w);
        float q0 = (p[0] + p[1]) + (p[2] + p[3]);
        float q1 = (p[4] + p[5]) + (p[6] + p[7]);
        float q2 = (p[8] + p[9]) + (p[10] + p[11]);
        float q3 = (p[12] + p[13]) + (p[14] + p[15]);
        A = (q0 + q1) + (q2 + q3);
    }

    // Argmin over codes: score = fl(fl(A - 2*dot) + ||e||^2), strict < keeps lowest index.
    float best = 3.4e38f;
    int bidx = 0;
    for (int c = 0; c < M; ++c) {
        const float* e = emb + c * D;   // wave-uniform address -> scalar loads
        float d0 = 0.f, d1 = 0.f, d2 = 0.f, d3 = 0.f;
#pragma unroll
        for (int k = 0; k < D; k += 4) {
            const float4 xq = xr[k >> 2];
            d0 = fmaf(e[k + 0], xq.x, d0);
            d1 = fmaf(e[k + 1], xq.y, d1);
            d2 = fmaf(e[k + 2], xq.z, d2);
            d3 = fmaf(e[k + 3], xq.w, d3);
        }
        const float dot = (d0 + d1) + (d2 + d3);
        const float score = fmaf(-2.0f, dot, A) + sE[c];
        if (score < best) { best = score; bidx = c; }
    }

    // Gather chosen code, write straight-through output, accumulate loss.
    const float* q = emb + bidx * D;    // per-thread gather (codebook is L1/L2 resident)
    float l0 = 0.f, l1 = 0.f, l2 = 0.f, l3 = 0.f;
    float4* ov = reinterpret_cast<float4*>(out + (size_t)i * D);
#pragma unroll
    for (int k = 0; k < D; k += 4) {
        const float4 xq = xr[k >> 2];
        const float q0 = q[k + 0], q1 = q[k + 1], q2 = q[k + 2], q3 = q[k + 3];
        const float e0 = xq.x - q0, e1 = xq.y - q1, e2 = xq.z - q2, e3 = xq.w - q3;
        l0 = fmaf(e0, e0, l0);
        l1 = fmaf(e1, e1, l1);
        l2 = fmaf(e2, e2, l2);
        l3 = fmaf(e3, e3, l3);
        float4 o;
        // ref: out = fl(x + fl(q - x)) == fl(x - fl(x - q)) bit-exactly
        o.x = xq.x - e0; o.y = xq.y - e1; o.z = xq.z - e2; o.w = xq.w - e3;
        ov[k >> 2] = o;
    }
    float lsum = (l0 + l1) + (l2 + l3);

    // Histogram of chosen indices.
    atomicAdd(&sHist[bidx], 1u);

    // Block-reduce loss: wave64 shuffle then cross-wave via LDS.
#pragma unroll
    for (int off = 32; off > 0; off >>= 1) lsum += __shfl_down(lsum, off);
    if ((tid & 63) == 0) sRed[tid >> 6] = lsum;
    __syncthreads();
    if (tid == 0) {
        const float tot = (sRed[0] + sRed[1]) + (sRed[2] + sRed[3]);
        atomicAdd(loss_sum, tot);
    }
    // Flush LDS histogram to global counts.
    for (int c = tid; c < M; c += 256) {
        const unsigned int h = sHist[c];
        if (h) atomicAdd(&counts[c], h);
    }
}

__global__ __launch_bounds__(512)
void vq_final(const unsigned int* __restrict__ counts,
              const float* __restrict__ loss_sum, float* __restrict__ out) {
    __shared__ float sRed[8];
    const int t = threadIdx.x;  // 512 threads, one per bin
    const float p = (float)counts[t] * (1.0f / 131072.0f);
    float term = p * logf(p + 1e-10f);
#pragma unroll
    for (int off = 32; off > 0; off >>= 1) term += __shfl_down(term, off);
    if ((t & 63) == 0) sRed[t >> 6] = term;
    __syncthreads();
    if (t == 0) {
        float s = 0.f;
#pragma unroll
        for (int w = 0; w < 8; ++w) s += sRed[w];
        out[N_ELEM]     = 0.25f * (loss_sum[0] * (1.0f / 8388608.0f));
        out[N_ELEM + 1] = expf(-s);
    }
}

extern "C" void kernel_launch(void* const* d_in, const int* in_sizes, int n_in,
                              void* d_out, int out_size, void* d_ws, size_t ws_size,
                              hipStream_t stream) {
    (void)in_sizes; (void)n_in; (void)out_size; (void)ws_size;
    const float* x   = (const float*)d_in[0];
    const float* emb = (const float*)d_in[1];
    float* out = (float*)d_out;
    float* loss_sum = (float*)d_ws;
    unsigned int* counts = (unsigned int*)d_ws + 1;

    hipMemsetAsync(d_ws, 0, (1 + M) * sizeof(float), stream);
    vq_main<<<dim3(N_VEC / 256), dim3(256), 0, stream>>>(x, emb, out, loss_sum, counts);
    vq_final<<<dim3(1), dim3(512), 0, stream>>>(counts, loss_sum, out);
}

// Round 2
// 203.976 us; speedup vs baseline: 1.5359x; 1.5359x over previous
//
#include <hip/hip_runtime.h>

// VQ-VAE quantization via 3-way bf16-split MFMA distance matmul. MI355X gfx950.
// x: [131072, 64] f32; emb: [512, 64] f32.
// d_out: quantized_st [8388608] | loss [1] | perplexity [1].
//
// score(i,c) = fl(fl(||x_i||^2 - 2*dot) + ||e_c||^2), dot from 6 bf16 MFMA products
// (hh, hm, mh, mm, hl, lh); dropped terms ~2^-27 rel => dot err ~5e-9, same order as
// fp32 reorder noise (R1 passed with absmax 0).

#define D      64
#define M      512
#define N_VEC  131072
#define N_ELEM 8388608

typedef __attribute__((ext_vector_type(8))) short short8;
typedef __attribute__((ext_vector_type(4))) float f32x4;

// ws byte layout: [0,4) loss f32 | [4,2052) counts u32[512] | [4096,6144) bnorm f32[512]
// | [8192, 8192+196608) bf16 planes: 3 x [512][64] u16 (h, m, l)

static __device__ __forceinline__ unsigned short f2bf(float f) {
    unsigned u = __float_as_uint(f);
    return (unsigned short)((u + 0x7FFFu + ((u >> 16) & 1u)) >> 16);  // RNE
}
static __device__ __forceinline__ float bf2f(unsigned short h) {
    return __uint_as_float(((unsigned)h) << 16);
}

__global__ __launch_bounds__(256)
void vq_prep(const float* __restrict__ emb, float* __restrict__ bnorm,
             unsigned short* __restrict__ planes) {
    const int c = blockIdx.x * 256 + threadIdx.x;   // grid 2 x 256 = 512 codes
    const float* e = emb + c * D;
    float s0 = 0.f, s1 = 0.f, s2 = 0.f, s3 = 0.f;   // same tree as R1 (passed absmax 0)
    for (int k = 0; k < D; k += 4) {
        float e0 = e[k], e1 = e[k + 1], e2 = e[k + 2], e3 = e[k + 3];
        s0 = fmaf(e0, e0, s0); s1 = fmaf(e1, e1, s1);
        s2 = fmaf(e2, e2, s2); s3 = fmaf(e3, e3, s3);
        float ev[4] = {e0, e1, e2, e3};
#pragma unroll
        for (int j = 0; j < 4; ++j) {
            float v = ev[j];
            unsigned short hh = f2bf(v);
            float r1 = v - bf2f(hh);
            unsigned short mm = f2bf(r1);
            float r2 = r1 - bf2f(mm);
            unsigned short ll = f2bf(r2);
            planes[0 * 32768 + c * D + k + j] = hh;
            planes[1 * 32768 + c * D + k + j] = mm;
            planes[2 * 32768 + c * D + k + j] = ll;
        }
    }
    bnorm[c] = (s0 + s1) + (s2 + s3);
}

__global__ __launch_bounds__(256, 2)
void vq_main(const float* __restrict__ x, const float* __restrict__ emb,
             const float* __restrict__ bnorm, const unsigned short* __restrict__ planes,
             float* __restrict__ out, float* __restrict__ loss_sum,
             unsigned int* __restrict__ counts) {
    // Row stride 72 shorts (144 B) -> bank stride 4, <=2-way conflict on b128 frag reads.
    __shared__ __align__(16) short sA[3 * 4608];   // 3 planes x 64 rows x 72
    __shared__ __align__(16) short sB[3 * 4608];
    __shared__ float sAn[64];
    __shared__ float sBn[64];
    __shared__ int   sIdx[64];
    __shared__ float sRed[4];

    const int tid = threadIdx.x;
    const size_t rowBase = (size_t)blockIdx.x * 64;

    // ---- Phase A1: stage x -> 3 bf16 split planes in LDS ----
    {
        const int v = tid >> 2, qt = tid & 3;
        const float4* xp = (const float4*)(x + (rowBase + v) * D + qt * 16);
        short8 h0, h1, m0, m1, l0, l1;
#pragma unroll
        for (int t = 0; t < 4; ++t) {
            float4 f = xp[t];
            float fv[4] = {f.x, f.y, f.z, f.w};
#pragma unroll
            for (int j = 0; j < 4; ++j) {
                float v0 = fv[j];
                unsigned short hh = f2bf(v0);
                float r1 = v0 - bf2f(hh);
                unsigned short mm = f2bf(r1);
                float r2 = r1 - bf2f(mm);
                unsigned short ll = f2bf(r2);
                int e = t * 4 + j;
                if (e < 8) { h0[e] = (short)hh; m0[e] = (short)mm; l0[e] = (short)ll; }
                else       { h1[e - 8] = (short)hh; m1[e - 8] = (short)mm; l1[e - 8] = (short)ll; }
            }
        }
        const int sb = v * 72 + qt * 16;
        *(short8*)&sA[0 * 4608 + sb] = h0;  *(short8*)&sA[0 * 4608 + sb + 8] = h1;
        *(short8*)&sA[1 * 4608 + sb] = m0;  *(short8*)&sA[1 * 4608 + sb + 8] = m1;
        *(short8*)&sA[2 * 4608 + sb] = l0;  *(short8*)&sA[2 * 4608 + sb + 8] = l1;
    }
    __syncthreads();

    // ---- Phase A2: ||x_row||^2 with R1's exact summation tree ----
    if (tid < 64) {
        const float4* xr = (const float4*)(x + (rowBase + tid) * D);  // L1-hot
        float p[16];
#pragma unroll
        for (int t = 0; t < 16; ++t) {
            float4 q = xr[t];
            p[t] = (q.x * q.x + q.y * q.y) + (q.z * q.z + q.w * q.w);
        }
        float q0 = (p[0] + p[1]) + (p[2] + p[3]);
        float q1 = (p[4] + p[5]) + (p[6] + p[7]);
        float q2 = (p[8] + p[9]) + (p[10] + p[11]);
        float q3 = (p[12] + p[13]) + (p[14] + p[15]);
        sAn[tid] = (q0 + q1) + (q2 + q3);
    }
    __syncthreads();

    const int lane = tid & 63, w = tid >> 6;
    const int kq = (lane >> 4) * 8;          // k-offset within 32-wide K-step

    // A-frags: fixed for whole kernel (24 VGPRs). A[m=lane&15][k=quad*8+j].
    short8 Af[3][2];
#pragma unroll
    for (int p = 0; p < 3; ++p)
#pragma unroll
        for (int s = 0; s < 2; ++s)
            Af[p][s] = *(const short8*)&sA[p * 4608 + (w * 16 + (lane & 15)) * 72 + s * 32 + kq];

    float Ar[4];
#pragma unroll
    for (int r = 0; r < 4; ++r) Ar[r] = sAn[w * 16 + (lane >> 4) * 4 + r];

    float best[4] = {3.4e38f, 3.4e38f, 3.4e38f, 3.4e38f};
    int   bidx[4] = {0, 0, 0, 0};

    // ---- K-loop over 8 chunks of 64 codes ----
    for (int c = 0; c < 8; ++c) {
        __syncthreads();   // previous chunk's sB reads done
        {
            const int ci = tid >> 2, qt = tid & 3;
#pragma unroll
            for (int p = 0; p < 3; ++p) {
                const short8* g = (const short8*)(planes + p * 32768 + (c * 64 + ci) * D + qt * 16);
                short8 v0 = g[0], v1 = g[1];
                *(short8*)&sB[p * 4608 + ci * 72 + qt * 16] = v0;
                *(short8*)&sB[p * 4608 + ci * 72 + qt * 16 + 8] = v1;
            }
            if (tid < 64) sBn[tid] = bnorm[c * 64 + tid];
        }
        __syncthreads();

#pragma unroll
        for (int ct = 0; ct < 4; ++ct) {
            const int bro = (ct * 16 + (lane & 15)) * 72;
            short8 Bf[3][2];
#pragma unroll
            for (int p = 0; p < 3; ++p)
#pragma unroll
                for (int s = 0; s < 2; ++s)
                    Bf[p][s] = *(const short8*)&sB[p * 4608 + bro + s * 32 + kq];

            f32x4 a1 = {0.f, 0.f, 0.f, 0.f}, a2 = a1, a3 = a1;
            // P1 = hh (largest)
            a1 = __builtin_amdgcn_mfma_f32_16x16x32_bf16(Af[0][0], Bf[0][0], a1, 0, 0, 0);
            a1 = __builtin_amdgcn_mfma_f32_16x16x32_bf16(Af[0][1], Bf[0][1], a1, 0, 0, 0);
            // P2 = hm + mh (~2^-9)
            a2 = __builtin_amdgcn_mfma_f32_16x16x32_bf16(Af[0][0], Bf[1][0], a2, 0, 0, 0);
            a2 = __builtin_amdgcn_mfma_f32_16x16x32_bf16(Af[0][1], Bf[1][1], a2, 0, 0, 0);
            a2 = __builtin_amdgcn_mfma_f32_16x16x32_bf16(Af[1][0], Bf[0][0], a2, 0, 0, 0);
            a2 = __builtin_amdgcn_mfma_f32_16x16x32_bf16(Af[1][1], Bf[0][1], a2, 0, 0, 0);
            // P3 = mm + hl + lh (~2^-18)
            a3 = __builtin_amdgcn_mfma_f32_16x16x32_bf16(Af[1][0], Bf[1][0], a3, 0, 0, 0);
            a3 = __builtin_amdgcn_mfma_f32_16x16x32_bf16(Af[1][1], Bf[1][1], a3, 0, 0, 0);
            a3 = __builtin_amdgcn_mfma_f32_16x16x32_bf16(Af[0][0], Bf[2][0], a3, 0, 0, 0);
            a3 = __builtin_amdgcn_mfma_f32_16x16x32_bf16(Af[0][1], Bf[2][1], a3, 0, 0, 0);
            a3 = __builtin_amdgcn_mfma_f32_16x16x32_bf16(Af[2][0], Bf[0][0], a3, 0, 0, 0);
            a3 = __builtin_amdgcn_mfma_f32_16x16x32_bf16(Af[2][1], Bf[0][1], a3, 0, 0, 0);

            const float Bn = sBn[ct * 16 + (lane & 15)];
            const int code = c * 64 + ct * 16 + (lane & 15);
#pragma unroll
            for (int r = 0; r < 4; ++r) {
                float dot = a1[r] + (a2[r] + a3[r]);
                float score = fmaf(-2.0f, dot, Ar[r]) + Bn;   // same rounding as R1
                if (score < best[r]) { best[r] = score; bidx[r] = code; }  // first-min tie-break
            }
        }
    }

    // ---- argmin reduce across the 16 col-lanes of each row-group ----
#pragma unroll
    for (int off = 1; off < 16; off <<= 1) {
#pragma unroll
        for (int r = 0; r < 4; ++r) {
            float ob = __shfl_xor(best[r], off, 64);
            int   oi = __shfl_xor(bidx[r], off, 64);
            if (ob < best[r] || (ob == best[r] && oi < bidx[r])) { best[r] = ob; bidx[r] = oi; }
        }
    }
    if ((lane & 15) == 0) {
#pragma unroll
        for (int r = 0; r < 4; ++r) sIdx[w * 16 + (lane >> 4) * 4 + r] = bidx[r];
    }
    __syncthreads();

    // ---- Epilogue: gather code, straight-through write, loss, histogram ----
    {
        const int v = tid >> 2, qt = tid & 3;
        const int code = sIdx[v];
        const float4* xr = (const float4*)(x + (rowBase + v) * D + qt * 16);
        const float4* qr = (const float4*)(emb + code * D + qt * 16);
        float4* ov = (float4*)(out + (rowBase + v) * D + qt * 16);
        float l0 = 0.f, l1 = 0.f, l2 = 0.f, l3 = 0.f;
#pragma unroll
        for (int t = 0; t < 4; ++t) {
            float4 xq = xr[t];
            float4 qq = qr[t];
            float e0 = xq.x - qq.x, e1 = xq.y - qq.y, e2 = xq.z - qq.z, e3 = xq.w - qq.w;
            l0 = fmaf(e0, e0, l0); l1 = fmaf(e1, e1, l1);
            l2 = fmaf(e2, e2, l2); l3 = fmaf(e3, e3, l3);
            float4 o;  // out = fl(x + fl(q - x)) == fl(x - fl(x - q))
            o.x = xq.x - e0; o.y = xq.y - e1; o.z = xq.z - e2; o.w = xq.w - e3;
            ov[t] = o;
        }
        float lsum = (l0 + l1) + (l2 + l3);
#pragma unroll
        for (int off = 32; off > 0; off >>= 1) lsum += __shfl_down(lsum, off, 64);
        if ((tid & 63) == 0) sRed[tid >> 6] = lsum;
        if (qt == 0) atomicAdd(&counts[code], 1u);   // 64/block over 512 bins: low contention
    }
    __syncthreads();
    if (tid == 0) atomicAdd(loss_sum, (sRed[0] + sRed[1]) + (sRed[2] + sRed[3]));
}

__global__ __launch_bounds__(512)
void vq_final(const unsigned int* __restrict__ counts,
              const float* __restrict__ loss_sum, float* __restrict__ out) {
    __shared__ float sRed[8];
    const int t = threadIdx.x;  // one per bin
    const float p = (float)counts[t] * (1.0f / 131072.0f);
    float term = p * logf(p + 1e-10f);
#pragma unroll
    for (int off = 32; off > 0; off >>= 1) term += __shfl_down(term, off, 64);
    if ((t & 63) == 0) sRed[t >> 6] = term;
    __syncthreads();
    if (t == 0) {
        float s = 0.f;
#pragma unroll
        for (int w = 0; w < 8; ++w) s += sRed[w];
        out[N_ELEM]     = 0.25f * (loss_sum[0] * (1.0f / 8388608.0f));
        out[N_ELEM + 1] = expf(-s);
    }
}

extern "C" void kernel_launch(void* const* d_in, const int* in_sizes, int n_in,
                              void* d_out, int out_size, void* d_ws, size_t ws_size,
                              hipStream_t stream) {
    (void)in_sizes; (void)n_in; (void)out_size; (void)ws_size;
    const float* x   = (const float*)d_in[0];
    const float* emb = (const float*)d_in[1];
    float* out = (float*)d_out;

    float*          loss  = (float*)d_ws;
    unsigned int*   cnts  = (unsigned int*)((char*)d_ws + 4);
    float*          bnorm = (float*)((char*)d_ws + 4096);
    unsigned short* plns  = (unsigned short*)((char*)d_ws + 8192);

    hipMemsetAsync(d_ws, 0, 4 + 512 * 4, stream);
    vq_prep<<<dim3(2), dim3(256), 0, stream>>>(emb, bnorm, plns);
    vq_main<<<dim3(N_VEC / 64), dim3(256), 0, stream>>>(x, emb, bnorm, plns, out, loss, cnts);
    vq_final<<<dim3(1), dim3(512), 0, stream>>>(cnts, loss, out);
}